// Round 19
// baseline (349.248 us; speedup 1.0000x reference)
//
#include <hip/hip_runtime.h>
#include <hip/hip_bf16.h>

#define B_SZ 2
#define SEQ 4096
#define DMODEL 1024
#define INTER 2048
#define NHEADS 32
#define HDIM 64
#define DSTATE 128
#define DCONV 4
#define CONVDIM 2304
#define PROJDIM 4384
#define CHUNK 256
#define NCHUNK 16
#define ROWS (B_SZ*SEQ)   // 8192
#define NGEMM 4352
#define NMAIN 4096        // main 8-phase cols (16 tiles; grid 512 = 2 clean rounds)

typedef __hip_bfloat16 bf16;
typedef short bfx8 __attribute__((ext_vector_type(8)));
typedef float f32x4 __attribute__((ext_vector_type(4)));

__device__ __forceinline__ float sigmoidf_(float x){ return 1.f/(1.f+expf(-x)); }
__device__ __forceinline__ float b2f(bf16 v){ return __bfloat162float(v); }
__device__ __forceinline__ bf16 f2b(float v){ return __float2bfloat16(v); }
__device__ __forceinline__ float bits2f(unsigned short u){ return __uint_as_float(((unsigned)u) << 16); }
__device__ __forceinline__ unsigned short f2bits(float v){ bf16 t = __float2bfloat16(v); return *(unsigned short*)&t; }

#define MFMA16(a,b,c) __builtin_amdgcn_mfma_f32_16x16x32_bf16(a,b,c,0,0,0)

// ---------------- fallback: zero d_out ----------------
__global__ void zero_out_kernel(float* o, int n){
  int i = blockIdx.x*256 + threadIdx.x;
  if (i < n) o[i] = 0.f;
}

// ---------------- merged cast+transpose for BOTH weights ----------------
__global__ __launch_bounds__(256) void transcast2_kernel(const float* __restrict__ w_in,
    bf16* __restrict__ w_inT, const float* __restrict__ w_out, bf16* __restrict__ w_outT){
  __shared__ float t[64][65];
  int blk = blockIdx.x, tid = threadIdx.x;
  const float* in; bf16* outT; int R, ld, c0, r0;
  if (blk < 1088){
    in = w_in;  outT = w_inT;  R = DMODEL; ld = PROJDIM;
    c0 = (blk % 68)*64; r0 = (blk / 68)*64;
  } else {
    int i = blk - 1088;
    in = w_out; outT = w_outT; R = INTER;  ld = DMODEL;
    c0 = (i & 15)*64;   r0 = (i >> 4)*64;
  }
  #pragma unroll
  for (int i = 0; i < 16; i++){
    int idx = tid + i*256;
    int r = idx >> 6, c = idx & 63;
    t[r][c] = in[(size_t)(r0+r)*ld + c0 + c];
  }
  __syncthreads();
  #pragma unroll
  for (int i = 0; i < 16; i++){
    int idx = tid + i*256;
    int c = idx >> 6, r = idx & 63;
    outT[(size_t)(c0+c)*R + r0 + r] = f2b(t[r][c]);
  }
}

// ================= 8-phase 256x256 MFMA GEMM (m201 template, T2+T3+T4+T5) =================
__device__ __forceinline__ void stage8(const bf16* __restrict__ g, int Kdim,
    int tile0, int k0, char* region, int h, int tid){
  #pragma unroll
  for (int l = 0; l < 2; l++){
    int o  = h*16384 + (l*512 + tid)*16;
    int os = o ^ (((o >> 7) & 7) << 4);
    const bf16* src = g + (size_t)(tile0 + (os >> 7))*Kdim + k0 + ((os & 127) >> 1);
    __builtin_amdgcn_global_load_lds(
      (const __attribute__((address_space(1))) void*)src,
      (__attribute__((address_space(3))) void*)(region + h*16384 + (l*512 + (tid >> 6)*64)*16),
      16, 0, 0);
  }
}
__device__ __forceinline__ bfx8 fr8(const char* region, int row, int colbyte){
  int o = row*128 + colbyte;
  o ^= ((row & 7) << 4);
  return *(const bfx8*)(region + o);
}

#define LGKM0  asm volatile("s_waitcnt lgkmcnt(0)" ::: "memory"); __builtin_amdgcn_sched_barrier(0)
#define VM4    asm volatile("s_waitcnt vmcnt(4)" ::: "memory")
#define VM0    asm volatile("s_waitcnt vmcnt(0)" ::: "memory")
#define BAR    __builtin_amdgcn_s_barrier()
#define PRIO1  __builtin_amdgcn_s_setprio(1)
#define PRIO0  __builtin_amdgcn_s_setprio(0)

#define MFMA_QUAD(MH, NH, BARR)                                                \
  PRIO1;                                                                       \
  _Pragma("unroll") for (int m = 0; m < 4; m++)                                \
    _Pragma("unroll") for (int n = 0; n < 2; n++)                              \
      _Pragma("unroll") for (int kk = 0; kk < 2; kk++)                         \
        acc[(MH)+m][(NH)+n] = MFMA16(aF[m][kk], BARR[n][kk], acc[(MH)+m][(NH)+n]); \
  PRIO0

#define GEMM8_BODY(K_, NBX_)                                                   \
  extern __shared__ char lds[];                                                \
  char* A0 = lds;          char* B0 = lds + 32768;                             \
  char* A1 = lds + 65536;  char* B1 = lds + 98304;                             \
  const int tid = threadIdx.x, lane = tid & 63, wid = tid >> 6;                \
  const int wm = wid >> 2, wn = wid & 3;                                       \
  int nb = (blockIdx.x & 7)*((int)gridDim.x >> 3) + (blockIdx.x >> 3);         \
  const int bx = nb % (NBX_), by = nb / (NBX_);                                \
  const int row0 = by*256, col0 = bx*256;                                      \
  f32x4 acc[8][4] = {};                                                        \
  bfx8 aF[4][2], b01[2][2], b23[2][2];                                         \
  const int frow = lane & 15;                                                  \
  const int fcb0 = (lane >> 4)*16;                                             \
  const int JLAST = (K_)/128 - 1;                                              \
  stage8(Bt, K_, col0, 0,  B0, 0, tid);                                        \
  stage8(Bt, K_, col0, 0,  B0, 1, tid);                                        \
  stage8(A,  K_, row0, 0,  A0, 0, tid);                                        \
  stage8(A,  K_, row0, 0,  A0, 1, tid);                                        \
  stage8(Bt, K_, col0, 64, B1, 0, tid);                                        \
  stage8(Bt, K_, col0, 64, B1, 1, tid);                                        \
  VM4;                                                                         \
  BAR;                                                                         \
  _Pragma("unroll 1")                                                          \
  for (int j = 0; j <= JLAST; j++){                                            \
    const int kO  = j*128 + 64;                                                \
    const int kS1 = (j*128 + 128) & ((K_) - 1);                                \
    const int kS2 = (j*128 + 192) & ((K_) - 1);                                \
    stage8(A, K_, row0, kO, A1, 0, tid);                                       \
    _Pragma("unroll") for (int m = 0; m < 4; m++)                              \
      _Pragma("unroll") for (int kk = 0; kk < 2; kk++)                         \
        aF[m][kk] = fr8(A0, wm*128 + m*16 + frow, kk*64 + fcb0);               \
    _Pragma("unroll") for (int n = 0; n < 2; n++)                              \
      _Pragma("unroll") for (int kk = 0; kk < 2; kk++)                         \
        b01[n][kk] = fr8(B0, wn*64 + n*16 + frow, kk*64 + fcb0);               \
    LGKM0;                                                                     \
    MFMA_QUAD(0, 0, b01);                                                      \
    BAR;                                                                       \
    stage8(A, K_, row0, kO, A1, 1, tid);                                       \
    _Pragma("unroll") for (int n = 0; n < 2; n++)                              \
      _Pragma("unroll") for (int kk = 0; kk < 2; kk++)                         \
        b23[n][kk] = fr8(B0, wn*64 + (n+2)*16 + frow, kk*64 + fcb0);           \
    LGKM0;                                                                     \
    MFMA_QUAD(0, 2, b23);                                                      \
    BAR;                                                                       \
    if (j < JLAST) stage8(Bt, K_, col0, kS1, B0, 0, tid);                      \
    _Pragma("unroll") for (int m = 0; m < 4; m++)                              \
      _Pragma("unroll") for (int kk = 0; kk < 2; kk++)                         \
        aF[m][kk] = fr8(A0, wm*128 + (m+4)*16 + frow, kk*64 + fcb0);           \
    LGKM0;                                                                     \
    MFMA_QUAD(4, 0, b01);                                                      \
    BAR;                                                                       \
    if (j < JLAST){ stage8(Bt, K_, col0, kS1, B0, 1, tid); VM4; }              \
    else { VM0; }                                                              \
    MFMA_QUAD(4, 2, b23);                                                      \
    BAR;                                                                       \
    if (j < JLAST) stage8(A, K_, row0, kS1, A0, 0, tid);                       \
    _Pragma("unroll") for (int m = 0; m < 4; m++)                              \
      _Pragma("unroll") for (int kk = 0; kk < 2; kk++)                         \
        aF[m][kk] = fr8(A1, wm*128 + m*16 + frow, kk*64 + fcb0);               \
    _Pragma("unroll") for (int n = 0; n < 2; n++)                              \
      _Pragma("unroll") for (int kk = 0; kk < 2; kk++)                         \
        b01[n][kk] = fr8(B1, wn*64 + n*16 + frow, kk*64 + fcb0);               \
    LGKM0;                                                                     \
    MFMA_QUAD(0, 0, b01);                                                      \
    BAR;                                                                       \
    if (j < JLAST) stage8(A, K_, row0, kS1, A0, 1, tid);                       \
    _Pragma("unroll") for (int n = 0; n < 2; n++)                              \
      _Pragma("unroll") for (int kk = 0; kk < 2; kk++)                         \
        b23[n][kk] = fr8(B1, wn*64 + (n+2)*16 + frow, kk*64 + fcb0);           \
    LGKM0;                                                                     \
    MFMA_QUAD(0, 2, b23);                                                      \
    BAR;                                                                       \
    if (j < JLAST) stage8(Bt, K_, col0, kS2, B1, 0, tid);                      \
    _Pragma("unroll") for (int m = 0; m < 4; m++)                              \
      _Pragma("unroll") for (int kk = 0; kk < 2; kk++)                         \
        aF[m][kk] = fr8(A1, wm*128 + (m+4)*16 + frow, kk*64 + fcb0);           \
    LGKM0;                                                                     \
    MFMA_QUAD(4, 0, b01);                                                      \
    BAR;                                                                       \
    if (j < JLAST) stage8(Bt, K_, col0, kS2, B1, 1, tid);                      \
    VM4;                                                                       \
    MFMA_QUAD(4, 2, b23);                                                      \
    BAR;                                                                       \
  }

#define SST_STRIDE 280

// main inproj: cols 0..4095 (grid 512 = 2 exact occupancy rounds)
__global__ __launch_bounds__(512, 2) void gemm8_inproj(const bf16* __restrict__ A,
    const bf16* __restrict__ Bt, bf16* __restrict__ z, bf16* __restrict__ xbc){
  GEMM8_BODY(DMODEL, 16)
  unsigned short* sst = (unsigned short*)lds;
  #pragma unroll 1
  for (int half = 0; half < 2; half++){
    if (wm == half){
      #pragma unroll
      for (int m = 0; m < 8; m++)
        #pragma unroll
        for (int n = 0; n < 4; n++)
          #pragma unroll
          for (int r = 0; r < 4; r++){
            int rl = m*16 + (lane>>4)*4 + r;
            sst[rl*SST_STRIDE + wn*64 + n*16 + (lane&15)] = f2bits(acc[m][n][r]);
          }
    }
    BAR;
    #pragma unroll
    for (int i = 0; i < 8; i++){
      int q = tid + i*512;
      int rl = q >> 5, c8 = (q & 31)*8;
      bfx8 v = *(const bfx8*)(sst + rl*SST_STRIDE + c8);
      int gr = row0 + half*128 + rl, gc = col0 + c8;
      if (gc < INTER) *(bfx8*)(z + (size_t)gr*INTER + gc) = v;
      else            *(bfx8*)(xbc + (size_t)gr*CONVDIM + (gc - INTER)) = v;
    }
    BAR;
  }
}

// ================= m97-structure GEMMs (128^2 tile) =================
#define MFMA_GEMM_BODY(K_, ROW0_, COL0_, EPILOGUE)                             \
  __shared__ unsigned short As[128*64];                                        \
  __shared__ unsigned short Bs[128*64];                                        \
  const int tid = threadIdx.x;                                                 \
  const int lane = tid & 63, wid = tid >> 6;                                   \
  const int wm = wid >> 1, wn = wid & 1;                                       \
  const int row0 = (ROW0_), col0 = (COL0_);                                    \
  f32x4 acc[4][4] = {};                                                        \
  const int rstg = wid*32 + ((lane>>3)&7);                                     \
  const int kstg = (lane&7)*8;                                                 \
  for (int k0 = 0; k0 < (K_); k0 += 64){                                       \
    _Pragma("unroll")                                                          \
    for (int j = 0; j < 4; j++){                                               \
      const bf16* gA = A + (size_t)(row0 + rstg + j*8)*(K_) + k0 + kstg;       \
      __builtin_amdgcn_global_load_lds(                                        \
        (const __attribute__((address_space(1))) void*)gA,                     \
        (__attribute__((address_space(3))) void*)(As + (wid*32 + j*8)*64),     \
        16, 0, 0);                                                             \
      const bf16* gB = Bt + (size_t)(col0 + rstg + j*8)*(K_) + k0 + kstg;      \
      __builtin_amdgcn_global_load_lds(                                        \
        (const __attribute__((address_space(1))) void*)gB,                     \
        (__attribute__((address_space(3))) void*)(Bs + (wid*32 + j*8)*64),     \
        16, 0, 0);                                                             \
    }                                                                          \
    __syncthreads();                                                           \
    _Pragma("unroll")                                                          \
    for (int kk = 0; kk < 2; kk++){                                            \
      bfx8 af[4], bfr[4];                                                      \
      _Pragma("unroll")                                                        \
      for (int m = 0; m < 4; m++)                                              \
        af[m] = *(const bfx8*)(As + (wm*64 + m*16 + (lane&15))*64              \
                               + kk*32 + (lane>>4)*8);                         \
      _Pragma("unroll")                                                        \
      for (int n = 0; n < 4; n++)                                              \
        bfr[n] = *(const bfx8*)(Bs + (wn*64 + n*16 + (lane&15))*64             \
                                + kk*32 + (lane>>4)*8);                        \
      _Pragma("unroll")                                                        \
      for (int m = 0; m < 4; m++)                                              \
        _Pragma("unroll")                                                      \
        for (int n = 0; n < 4; n++)                                            \
          acc[m][n] = MFMA16(af[m], bfr[n], acc[m][n]);                        \
    }                                                                          \
    __syncthreads();                                                           \
  }                                                                            \
  _Pragma("unroll")                                                            \
  for (int m = 0; m < 4; m++){                                                 \
    int row = row0 + wm*64 + m*16 + (lane>>4)*4;                               \
    _Pragma("unroll")                                                          \
    for (int n = 0; n < 4; n++){                                               \
      int col = col0 + wn*64 + n*16 + (lane&15);                               \
      _Pragma("unroll")                                                        \
      for (int r = 0; r < 4; r++){                                             \
        float v = acc[m][n][r];                                                \
        int rr = row + r;                                                      \
        EPILOGUE                                                               \
      }                                                                        \
    }                                                                          \
  }

__global__ __launch_bounds__(256) void gemm_mfma_inproj(const bf16* __restrict__ A,
    const bf16* __restrict__ Bt, bf16* __restrict__ z, bf16* __restrict__ xbc){
  MFMA_GEMM_BODY(DMODEL, blockIdx.y*128, blockIdx.x*128,
    if (col < INTER) z[(size_t)rr*INTER + col] = f2b(v);
    else             xbc[(size_t)rr*CONVDIM + (col - INTER)] = f2b(v);
  )
}
// strip: inproj cols 4096..4351 (xbc cols 2048..2303); Bt pre-offset
__global__ __launch_bounds__(256) void gemm_mfma_strip(const bf16* __restrict__ A,
    const bf16* __restrict__ Bt, bf16* __restrict__ xbc){
  MFMA_GEMM_BODY(DMODEL, blockIdx.y*128, blockIdx.x*128,
    xbc[(size_t)rr*CONVDIM + 2048 + col] = f2b(v);
  )
}
// outproj: 1D grid 512, per-XCD row-chunk swizzle
__global__ __launch_bounds__(256) void gemm_mfma_outproj(const bf16* __restrict__ A,
    const bf16* __restrict__ Bt, float* __restrict__ C){
  int nbo = (blockIdx.x & 7)*64 + (blockIdx.x >> 3);
  MFMA_GEMM_BODY(INTER, (nbo >> 3)*128, (nbo & 7)*128,
    C[(size_t)rr*DMODEL + col] = v;
  )
}

// ---------------- split-K fp32 dt GEMM + fused u->bf16 cast ----------------
__global__ __launch_bounds__(256) void dt_partial(const float* __restrict__ u,
    const float* __restrict__ w_in, float* __restrict__ partial,
    unsigned short* __restrict__ u_bf){
  __shared__ float wsm[128][33];
  __shared__ float us[32][133];
  int ks = blockIdx.x, row0 = blockIdx.y*32;
  int k0 = ks*128;
  int tid = threadIdx.x;
  #pragma unroll
  for (int i = 0; i < 16; i++){
    int idx = tid + i*256;
    wsm[idx >> 5][idx & 31] = w_in[(size_t)(k0 + (idx >> 5))*PROJDIM + NGEMM + (idx & 31)];
  }
  #pragma unroll
  for (int i = 0; i < 4; i++){
    int idx = tid + i*256;
    int r = idx >> 5, c4 = idx & 31;
    float4 v = *(const float4*)(u + (size_t)(row0 + r)*DMODEL + k0 + c4*4);
    us[r][c4*4+0] = v.x; us[r][c4*4+1] = v.y; us[r][c4*4+2] = v.z; us[r][c4*4+3] = v.w;
    ushort4 w;
    w.x = f2bits(v.x); w.y = f2bits(v.y); w.z = f2bits(v.z); w.w = f2bits(v.w);
    *(ushort4*)(u_bf + (size_t)(row0 + r)*DMODEL + k0 + c4*4) = w;
  }
  __syncthreads();
  int col = tid & 31, r0 = tid >> 5;
  float acc[4] = {};
  #pragma unroll 4
  for (int kk4 = 0; kk4 < 32; kk4++){
    float4 uv[4];
    #pragma unroll
    for (int i = 0; i < 4; i++)
      uv[i] = *(const float4*)&us[r0 + i*8][kk4*4];
    #pragma unroll
    for (int j = 0; j < 4; j++){
      float wv = wsm[kk4*4 + j][col];
      #pragma unroll
      for (int i = 0; i < 4; i++){
        float uvj = (j == 0) ? uv[i].x : (j == 1) ? uv[i].y : (j == 2) ? uv[i].z : uv[i].w;
        acc[i] = fmaf(uvj, wv, acc[i]);
      }
    }
  }
  #pragma unroll
  for (int i = 0; i < 4; i++)
    partial[((size_t)ks*ROWS + row0 + r0 + i*8)*NHEADS + col] = acc[i];
}

// ---------------- conv1d + silu + split (sliding-window) ----------------
__global__ __launch_bounds__(256) void conv_kernel(const bf16* __restrict__ xbc,
    const float* __restrict__ cw, const float* __restrict__ cb,
    bf16* __restrict__ x, bf16* __restrict__ Bm, bf16* __restrict__ Cm){
  int ch = blockIdx.x*256 + threadIdx.x;
  int t0 = blockIdx.y*64;
  int b  = blockIdx.z;
  float w0 = cw[ch*4+0], w1 = cw[ch*4+1], w2 = cw[ch*4+2], w3 = cw[ch*4+3];
  float bia = cb[ch];
  const bf16* src = xbc + (size_t)(b*SEQ)*CONVDIM + ch;
  float xm3 = 0.f, xm2 = 0.f, xm1 = 0.f;
  if (t0 > 0){
    xm3 = b2f(src[(size_t)(t0-3)*CONVDIM]);
    xm2 = b2f(src[(size_t)(t0-2)*CONVDIM]);
    xm1 = b2f(src[(size_t)(t0-1)*CONVDIM]);
  }
  bf16* dst; size_t dstride;
  if (ch < INTER)             { dst = x  + (size_t)(b*SEQ + t0)*INTER  + ch;                 dstride = INTER; }
  else if (ch < INTER+DSTATE) { dst = Bm + (size_t)(b*SEQ + t0)*DSTATE + (ch-INTER);         dstride = DSTATE; }
  else                        { dst = Cm + (size_t)(b*SEQ + t0)*DSTATE + (ch-INTER-DSTATE);  dstride = DSTATE; }
  #pragma unroll 4
  for (int i = 0; i < 64; i++){
    float xc = b2f(src[(size_t)(t0+i)*CONVDIM]);
    float acc = bia;
    acc = fmaf(xm3, w0, acc);
    acc = fmaf(xm2, w1, acc);
    acc = fmaf(xm1, w2, acc);
    acc = fmaf(xc,  w3, acc);
    float v = acc * sigmoidf_(acc);
    dst[(size_t)i*dstride] = f2b(v);
    xm3 = xm2; xm2 = xm1; xm1 = xc;
  }
}

// ---------------- fused: 8-way reduce + bias + softplus -> dt; cumsum(dt*A) -> Acum ----------------
// NOTE: dt/Acum alias the xbc TAIL — must launch after conv.
__global__ __launch_bounds__(256) void acum_fused(const float* __restrict__ partial,
    const float* __restrict__ dt_bias, const float* __restrict__ A_log,
    float* __restrict__ dt, float* __restrict__ Acum){
  int bi = blockIdx.x;
  int c = bi & 15; int h = (bi >> 4) & 31; int b = bi >> 9;
  int l = threadIdx.x;
  __shared__ float sbuf[CHUNK];
  int t = c*CHUNK + l;
  size_t idx = (size_t)(b*SEQ + t)*NHEADS + h;
  float s = dt_bias[h];
  #pragma unroll
  for (int ks = 0; ks < 8; ks++)
    s += partial[(size_t)ks*ROWS*NHEADS + idx];
  float v = (s > 20.f) ? s : log1pf(expf(s));
  dt[idx] = v;
  float A = -expf(A_log[h]);
  sbuf[l] = v * A;
  __syncthreads();
  for (int off = 1; off < CHUNK; off <<= 1){
    float add = (l >= off) ? sbuf[l-off] : 0.f;
    __syncthreads();
    sbuf[l] += add;
    __syncthreads();
  }
  Acum[(size_t)bi*CHUNK + l] = sbuf[l];
}

// ---------------- head-shared scores (dense task list): S[bc][l][s] = C·B^T ----------------
__global__ __launch_bounds__(256) void scores_mfma(const bf16* __restrict__ Bm,
    const bf16* __restrict__ Cm, bf16* __restrict__ S){
  int bc = blockIdx.x;
  int b = bc >> 4, c = bc & 15;
  int tid = threadIdx.x, lane = tid & 63;
  int task = blockIdx.y*4 + (tid >> 6);
  if (task >= 10) return;
  int rb = (task >= 6) ? 3 : (task >= 3) ? 2 : (task >= 1) ? 1 : 0;
  int j = task - rb*(rb+1)/2;
  const bf16* Crow = Cm + (size_t)(b*SEQ + c*CHUNK)*DSTATE;
  const bf16* Brow = Bm + (size_t)(b*SEQ + c*CHUNK)*DSTATE;
  f32x4 acc[4][4] = {};
  #pragma unroll
  for (int kk = 0; kk < 4; kk++){
    bfx8 af[4], bfr[4];
    #pragma unroll
    for (int m = 0; m < 4; m++)
      af[m] = *(const bfx8*)(Crow + (size_t)(rb*64 + m*16 + (lane&15))*DSTATE + kk*32 + (lane>>4)*8);
    #pragma unroll
    for (int n = 0; n < 4; n++)
      bfr[n] = *(const bfx8*)(Brow + (size_t)(j*64 + n*16 + (lane&15))*DSTATE + kk*32 + (lane>>4)*8);
    #pragma unroll
    for (int m = 0; m < 4; m++)
      #pragma unroll
      for (int n = 0; n < 4; n++)
        acc[m][n] = MFMA16(af[m], bfr[n], acc[m][n]);
  }
  bf16* dst = S + (size_t)bc*CHUNK*CHUNK;
  #pragma unroll
  for (int m = 0; m < 4; m++)
    #pragma unroll
    for (int n = 0; n < 4; n++)
      #pragma unroll
      for (int r = 0; r < 4; r++)
        dst[(size_t)(rb*64 + m*16 + (lane>>4)*4 + r)*CHUNK + j*64 + n*16 + (lane&15)]
          = f2b(acc[m][n][r]);
}

// ---------------- build XW_T + BT ----------------
__global__ __launch_bounds__(256) void xwt_kernel(const bf16* __restrict__ x,
    const bf16* __restrict__ Bm, const float* __restrict__ dt,
    const float* __restrict__ Acum, bf16* __restrict__ xwt, bf16* __restrict__ bt){
  int pt = blockIdx.x, tt = blockIdx.y, b = blockIdx.z;
  int tid = threadIdx.x;
  __shared__ unsigned short tile[64][72];
  __shared__ float wf[64];
  int t0 = tt*64;
  if (pt < 32){
    int h = pt, c = t0 >> 8;
    if (tid < 64){
      const float* AcB = Acum + ((size_t)(b*NHEADS + h)*NCHUNK + c)*CHUNK;
      int t = t0 + tid;
      wf[tid] = dt[(size_t)(b*SEQ + t)*NHEADS + h] * expf(AcB[255] - AcB[t & 255]);
    }
    __syncthreads();
    const bf16* src = x + (size_t)(b*SEQ + t0)*INTER + pt*64;
    #pragma unroll
    for (int i = 0; i < 2; i++){
      int u = tid + i*256;
      int r = u >> 3, po = (u & 7)*8;
      bfx8 v = *(const bfx8*)(src + (size_t)r*INTER + po);
      float d = wf[r];
      #pragma unroll
      for (int j = 0; j < 8; j++)
        tile[r][po + j] = f2bits(bits2f((unsigned short)v[j]) * d);
    }
    __syncthreads();
    bf16* dst = xwt + ((size_t)(b*INTER) + pt*64)*SEQ + t0;
    #pragma unroll
    for (int i = 0; i < 2; i++){
      int u = tid + i*256;
      int p = u >> 3, tc = (u & 7)*8;
      bfx8 v;
      #pragma unroll
      for (int j = 0; j < 8; j++) v[j] = (short)tile[tc + j][p];
      *(bfx8*)(dst + (size_t)p*SEQ + tc) = v;
    }
  } else {
    int n0 = (pt - 32)*64;
    const bf16* src = Bm + (size_t)(b*SEQ + t0)*DSTATE + n0;
    #pragma unroll
    for (int i = 0; i < 2; i++){
      int u = tid + i*256;
      int r = u >> 3, po = (u & 7)*8;
      bfx8 v = *(const bfx8*)(src + (size_t)r*DSTATE + po);
      *(bfx8*)&tile[r][po] = v;
    }
    __syncthreads();
    bf16* dst = bt + ((size_t)(b*DSTATE) + n0)*SEQ + t0;
    #pragma unroll
    for (int i = 0; i < 2; i++){
      int u = tid + i*256;
      int p = u >> 3, tc = (u & 7)*8;
      bfx8 v;
      #pragma unroll
      for (int j = 0; j < 8; j++) v[j] = (short)tile[tc + j][p];
      *(bfx8*)(dst + (size_t)p*SEQ + tc) = v;
    }
  }
}

// ---------------- MFMA chunk-states ----------------
__global__ __launch_bounds__(256) void chunk_states_mfma(const bf16* __restrict__ xwt,
    const bf16* __restrict__ bt, float* __restrict__ states){
  int bi = blockIdx.x;
  int h = bi & 31; int c = (bi >> 5) & 15; int b = bi >> 9;
  int tid = threadIdx.x, lane = tid & 63, w = tid >> 6;
  int wm = w >> 1, wn = w & 1;
  const bf16* Arow = xwt + ((size_t)(b*INTER) + h*64)*SEQ + c*CHUNK;
  const bf16* Brow = bt + (size_t)(b*DSTATE)*SEQ + c*CHUNK;
  f32x4 acc[2][4] = {};
  #pragma unroll
  for (int kk = 0; kk < 8; kk++){
    bfx8 af[2], bfr[4];
    #pragma unroll
    for (int m = 0; m < 2; m++)
      af[m] = *(const bfx8*)(Arow + (size_t)(wm*32 + m*16 + (lane&15))*SEQ + kk*32 + (lane>>4)*8);
    #pragma unroll
    for (int n = 0; n < 4; n++)
      bfr[n] = *(const bfx8*)(Brow + (size_t)(wn*64 + n*16 + (lane&15))*SEQ + kk*32 + (lane>>4)*8);
    #pragma unroll
    for (int m = 0; m < 2; m++)
      #pragma unroll
      for (int n = 0; n < 4; n++)
        acc[m][n] = MFMA16(af[m], bfr[n], acc[m][n]);
  }
  float* dst = states + (size_t)bi*HDIM*DSTATE;
  #pragma unroll
  for (int m = 0; m < 2; m++)
    #pragma unroll
    for (int n = 0; n < 4; n++)
      #pragma unroll
      for (int r = 0; r < 4; r++){
        int p = wm*32 + m*16 + (lane>>4)*4 + r;
        int nn = wn*64 + n*16 + (lane&15);
        dst[(size_t)p*DSTATE + nn] = acc[m][n][r];
      }
}

// ---------------- inter-chunk scan ----------------
__global__ __launch_bounds__(256) void scan_kernel(float* __restrict__ states,
    const float* __restrict__ Acum){
  int idx = blockIdx.x*256 + threadIdx.x;
  int n = idx & 127; int p = (idx >> 7) & 63; int h = (idx >> 13) & 31; int b = idx >> 18;
  float R = 0.f;
  for (int c = 0; c < NCHUNK; c++){
    size_t o = (((size_t)((b*NCHUNK + c)*NHEADS + h))*HDIM + p)*DSTATE + n;
    float s = states[o];
    states[o] = R;
    float dA = expf(Acum[((size_t)(b*NHEADS + h)*NCHUNK + c)*CHUNK + CHUNK-1]);
    R = R*dA + s;
  }
}

// ================= fused MFMA Y kernel (wave-balanced: wave w owns rows m*64+w*16) =================
__global__ __launch_bounds__(256, 3) void ydiag_mfma(
    const bf16* x, const float* __restrict__ dt,
    const float* __restrict__ Acum, const bf16* __restrict__ Sg,
    const bf16* __restrict__ Cm, const float* __restrict__ states,
    const float* __restrict__ Dp, bf16* y){
  int bi = blockIdx.x;
  int h = bi & 31; int c = (bi >> 5) & 15; int b = bi >> 9;
  int bc = b*NCHUNK + c;
  int tid = threadIdx.x, lane = tid & 63, w = tid >> 6;

  __shared__ unsigned short XdtT[64*264];
  __shared__ unsigned short pool[128*72];
  __shared__ float Acs[CHUNK];
  __shared__ float dts[CHUNK];

  const float* AcBase = Acum + ((size_t)(b*NHEADS + h)*NCHUNK + c)*CHUNK;
  Acs[tid] = AcBase[tid];
  dts[tid] = dt[(size_t)(b*SEQ + c*CHUNK + tid)*NHEADS + h];
  {
    const float* src = states + (size_t)bi*HDIM*DSTATE;
    #pragma unroll
    for (int i = 0; i < 8; i++){
      int q = tid + i*256;
      float4 v = ((const float4*)src)[q];
      int p = q >> 5, n = (q & 31)*4;
      ushort4 o;
      o.x = f2bits(v.x); o.y = f2bits(v.y); o.z = f2bits(v.z); o.w = f2bits(v.w);
      *(ushort4*)(pool + p*136 + n) = o;
    }
  }
  __syncthreads();

  const bf16* Crow = Cm + (size_t)(b*SEQ + c*CHUNK)*DSTATE;

  // off-GEMM: rows for wave = m*64 + w*16 (balanced interleave)
  f32x4 accY[4][4] = {};
  #pragma unroll
  for (int kk = 0; kk < 4; kk++){
    bfx8 af[4], bfr[4];
    #pragma unroll
    for (int m = 0; m < 4; m++)
      af[m] = *(const bfx8*)(Crow + (size_t)(m*64 + w*16 + (lane&15))*DSTATE + kk*32 + (lane>>4)*8);
    #pragma unroll
    for (int n = 0; n < 4; n++)
      bfr[n] = *(const bfx8*)(pool + (n*16 + (lane&15))*136 + kk*32 + (lane>>4)*8);
    #pragma unroll
    for (int m = 0; m < 4; m++)
      #pragma unroll
      for (int n = 0; n < 4; n++)
        accY[m][n] = MFMA16(af[m], bfr[n], accY[m][n]);
  }
  {
    float eAl[4][4];
    #pragma unroll
    for (int m = 0; m < 4; m++)
      #pragma unroll
      for (int r = 0; r < 4; r++)
        eAl[m][r] = expf(Acs[m*64 + w*16 + (lane>>4)*4 + r]);
    #pragma unroll
    for (int m = 0; m < 4; m++)
      #pragma unroll
      for (int n = 0; n < 4; n++)
        #pragma unroll
        for (int r = 0; r < 4; r++)
          accY[m][n][r] *= eAl[m][r];
  }
  __syncthreads();

  #pragma unroll 1
  for (int q = 0; q < 2; q++){
    const bf16* xg = x + (size_t)(b*SEQ + c*CHUNK + q*128)*INTER + h*HDIM;
    #pragma unroll
    for (int i = 0; i < 4; i++){
      int u = tid + i*256;
      int s = u >> 3, p0 = (u & 7)*8;
      bfx8 v = *(const bfx8*)(xg + (size_t)s*INTER + p0);
      float d = dts[q*128 + s];
      bfx8 o;
      #pragma unroll
      for (int j = 0; j < 8; j++)
        o[j] = (short)f2bits(bits2f((unsigned short)v[j]) * d);
      *(bfx8*)(pool + s*72 + p0) = o;
    }
    __syncthreads();
    {
      int p = tid & 63, sb = tid >> 6;
      #pragma unroll
      for (int i = 0; i < 4; i++){
        int s0 = (sb + i*4)*8;
        bfx8 v;
        #pragma unroll
        for (int j = 0; j < 8; j++)
          v[j] = (short)pool[(s0 + j)*72 + p];
        *(bfx8*)(XdtT + p*264 + q*128 + s0) = v;
      }
    }
    __syncthreads();
  }

  // stripe loop: j outer (load XdtT fragments once), m inner (j <= m)
  // per-wave work identical: 10 (m,j) passes x 8 MFMA. Accumulation order per
  // output element unchanged (off-GEMM, then stripes ascending) -> bit-identical.
  const bf16* Sbase = Sg + (size_t)bc*CHUNK*CHUNK;
  float Dh = Dp[h];
  #pragma unroll 1
  for (int j = 0; j < 4; j++){
    int s0 = j*64;
    bfx8 bfr[4][2];
    #pragma unroll
    for (int kk = 0; kk < 2; kk++)
      #pragma unroll
      for (int n = 0; n < 4; n++)
        bfr[n][kk] = *(const bfx8*)(XdtT + (n*16 + (lane&15))*264 + s0 + kk*32 + (lane>>4)*8);
    float m_ = Acs[s0 + 63];
    float colf[2][8];
    #pragma unroll
    for (int kk = 0; kk < 2; kk++)
      #pragma unroll
      for (int t = 0; t < 8; t++)
        colf[kk][t] = expf(m_ - Acs[s0 + kk*32 + (lane>>4)*8 + t]);
    #pragma unroll
    for (int m = 3; m >= 0; m--){
      if (m < j) continue;
      int lrow = m*64 + w*16 + (lane&15);
      bfx8 wfr[2];
      if (j < m){
        float rowf = expf(Acs[lrow] - m_);
        #pragma unroll
        for (int kk = 0; kk < 2; kk++){
          bfx8 raw = *(const bfx8*)(Sbase + (size_t)lrow*CHUNK + s0 + kk*32 + (lane>>4)*8);
          bfx8 o;
          #pragma unroll
          for (int t = 0; t < 8; t++)
            o[t] = (short)f2bits(bits2f((unsigned short)raw[t]) * rowf * colf[kk][t]);
          wfr[kk] = o;
        }
      } else {
        float Al = Acs[lrow];
        #pragma unroll
        for (int kk = 0; kk < 2; kk++){
          bfx8 raw = *(const bfx8*)(Sbase + (size_t)lrow*CHUNK + s0 + kk*32 + (lane>>4)*8);
          bfx8 o;
          #pragma unroll
          for (int t = 0; t < 8; t++){
            int sg = s0 + kk*32 + (lane>>4)*8 + t;
            float v;
            if (sg > lrow)       v = 0.f;
            else if (sg == lrow) v = bits2f((unsigned short)raw[t]) + Dh/dts[lrow];
            else                 v = bits2f((unsigned short)raw[t]) * expf(Al - Acs[sg]);
            o[t] = (short)f2bits(v);
          }
          wfr[kk] = o;
        }
      }
      #pragma unroll
      for (int kk = 0; kk < 2; kk++)
        #pragma unroll
        for (int n = 0; n < 4; n++)
          accY[m][n] = MFMA16(wfr[kk], bfr[n][kk], accY[m][n]);
    }
  }
  // epilogue: rows m*64 + w*16
  bf16* yg = y + (size_t)(b*SEQ + c*CHUNK)*INTER + h*HDIM;
  #pragma unroll
  for (int m = 0; m < 4; m++)
    #pragma unroll
    for (int n = 0; n < 4; n++)
      #pragma unroll
      for (int r = 0; r < 4; r++)
        yg[(size_t)(m*64 + w*16 + (lane>>4)*4 + r)*INTER + n*16 + (lane&15)]
          = f2b(accY[m][n][r]);
}

// ---------------- gate + RMSNorm (vectorized bfx8 loads/stores) ----------------
__global__ __launch_bounds__(256) void gatenorm_kernel(bf16* __restrict__ y,
    const bf16* __restrict__ z, const float* __restrict__ nw){
  int row = blockIdx.x;
  const bf16* zr = z + (size_t)row*INTER;
  bf16* yr = y + (size_t)row*INTER;
  int tid = threadIdx.x;
  bfx8 zv = *(const bfx8*)(zr + tid*8);
  bfx8 yv = *(const bfx8*)(yr + tid*8);
  float g[8]; float ss = 0.f;
  #pragma unroll
  for (int j = 0; j < 8; j++){
    float zf = bits2f((unsigned short)zv[j]);
    float gv = bits2f((unsigned short)yv[j]) * zf * sigmoidf_(zf);
    g[j] = gv; ss += gv*gv;
  }
  #pragma unroll
  for (int off = 32; off > 0; off >>= 1) ss += __shfl_down(ss, off);
  __shared__ float red[4];
  __shared__ float stot;
  int lane = tid & 63, wid = tid >> 6;
  if (lane == 0) red[wid] = ss;
  __syncthreads();
  if (tid == 0) stot = rsqrtf((red[0]+red[1]+red[2]+red[3]) * (1.f/INTER) + 1e-5f);
  __syncthreads();
  float sc = stot;
  float4 nw0 = *(const float4*)(nw + tid*8);
  float4 nw1 = *(const float4*)(nw + tid*8 + 4);
  bfx8 o;
  o[0] = (short)f2bits(g[0]*sc*nw0.x);
  o[1] = (short)f2bits(g[1]*sc*nw0.y);
  o[2] = (short)f2bits(g[2]*sc*nw0.z);
  o[3] = (short)f2bits(g[3]*sc*nw0.w);
  o[4] = (short)f2bits(g[4]*sc*nw1.x);
  o[5] = (short)f2bits(g[5]*sc*nw1.y);
  o[6] = (short)f2bits(g[6]*sc*nw1.z);
  o[7] = (short)f2bits(g[7]*sc*nw1.w);
  *(bfx8*)(yr + tid*8) = o;
}

extern "C" void kernel_launch(void* const* d_in, const int* in_sizes, int n_in,
                              void* d_out, int out_size, void* d_ws, size_t ws_size,
                              hipStream_t stream){
  const float* u    = (const float*)d_in[0];
  const float* w_in = (const float*)d_in[1];
  const float* cw   = (const float*)d_in[2];
  const float* cb   = (const float*)d_in[3];
  const float* dtb  = (const float*)d_in[4];
  const float* Alog = (const float*)d_in[5];
  const float* Dp   = (const float*)d_in[6];
  const float* nw   = (const float*)d_in[7];
  const float* w_out= (const float*)d_in[8];
  float* out = (float*)d_out;
  char* ws = (char*)d_ws;

  // layout (bytes)
  const size_t OFF_Z     = 0;
  const size_t OFF_XBC   = 33554432;
  const size_t OFF_DT    = 67108864;       // xbc TAIL — write only after conv!
  const size_t OFF_ACUM  = 68157440;       // xbc TAIL — write only after conv!
  const size_t OFF_X     = 71303168;       // y aliases
  const size_t OFF_UBF   = 104857600;      // XW_T aliases after inproj
  const size_t OFF_WINT  = 121634816;
  const size_t OFF_XWT   = 104857600;
  const size_t OFF_BM    = 138412032;
  const size_t OFF_CM    = 140509184;
  const size_t OFF_BT    = 143654912;
  const size_t OFF_WOUTT = 145752064;
  const size_t OFF_PART  = 149946368;      // S aliases after acum_fused
  const size_t NEED      = 158334976;

  if (ws_size < NEED){
    zero_out_kernel<<<(out_size + 255)/256, 256, 0, stream>>>(out, out_size);
    return;
  }

  bf16*  z      = (bf16*)(ws + OFF_Z);
  bf16*  xbc    = (bf16*)(ws + OFF_XBC);
  float* states = (float*)(ws + OFF_XBC);
  float* dt     = (float*)(ws + OFF_DT);
  float* Acum   = (float*)(ws + OFF_ACUM);
  bf16*  x      = (bf16*)(ws + OFF_X);
  bf16*  y      = (bf16*)(ws + OFF_X);
  bf16*  u_bf   = (bf16*)(ws + OFF_UBF);
  bf16*  w_inT  = (bf16*)(ws + OFF_WINT);
  bf16*  xwt    = (bf16*)(ws + OFF_XWT);
  bf16*  Bm     = (bf16*)(ws + OFF_BM);
  bf16*  Cm     = (bf16*)(ws + OFF_CM);
  bf16*  bt     = (bf16*)(ws + OFF_BT);
  bf16*  w_outT = (bf16*)(ws + OFF_WOUTT);
  float* part   = (float*)(ws + OFF_PART);
  bf16*  S      = (bf16*)(ws + OFF_PART);

  bool use8 = true;
  if (hipFuncSetAttribute((const void*)gemm8_inproj,
        hipFuncAttributeMaxDynamicSharedMemorySize, 131072) != hipSuccess) use8 = false;

  // 1) split-K dt partials + fused u->bf16 cast
  dt_partial<<<dim3(8, ROWS/32), 256, 0, stream>>>(u, w_in, part, (unsigned short*)u_bf);
  // 2) merged transcast
  transcast2_kernel<<<1600, 256, 0, stream>>>(w_in, w_inT, w_out, w_outT);
  // 3) inproj GEMM: main + strip
  if (use8){
    gemm8_inproj<<<512, 512, 131072, stream>>>(u_bf, w_inT, z, xbc);
    gemm_mfma_strip<<<dim3(2, ROWS/128), 256, 0, stream>>>(u_bf, w_inT + (size_t)NMAIN*DMODEL, xbc);
  } else {
    gemm_mfma_inproj<<<dim3(NGEMM/128, ROWS/128), 256, 0, stream>>>(u_bf, w_inT, z, xbc);
  }
  // 4) conv (MUST precede acum_fused: dt/Acum alias xbc tail)
  conv_kernel<<<dim3(9, SEQ/64, B_SZ), 256, 0, stream>>>(xbc, cw, cb, x, Bm, Cm);
  // 5) reduce+softplus -> dt, cumsum -> Acum
  acum_fused<<<B_SZ*NHEADS*NCHUNK, 256, 0, stream>>>(part, dtb, Alog, dt, Acum);
  // 6) head-shared scores
  scores_mfma<<<dim3(B_SZ*NCHUNK, 3), 256, 0, stream>>>(Bm, Cm, S);
  // 7) weighted transpose XW_T + BT
  xwt_kernel<<<dim3(34, 64, 2), 256, 0, stream>>>(x, Bm, dt, Acum, xwt, bt);
  // 8) MFMA chunk-states
  chunk_states_mfma<<<B_SZ*NCHUNK*NHEADS, 256, 0, stream>>>(xwt, bt, states);
  // 9) inter-chunk scan
  scan_kernel<<<(B_SZ*NHEADS*HDIM*DSTATE)/256, 256, 0, stream>>>(states, Acum);
  // 10) fused MFMA Y (wave-balanced)
  ydiag_mfma<<<B_SZ*NCHUNK*NHEADS, 256, 0, stream>>>(x, dt, Acum, S, Cm, states, Dp, y);
  // 11) gate + RMSNorm
  gatenorm_kernel<<<ROWS, 256, 0, stream>>>(y, z, nw);
  // 12) out_proj
  gemm_mfma_outproj<<<512, 256, 0, stream>>>(y, w_outT, out);
}

// Round 20
// 342.638 us; speedup vs baseline: 1.0193x; 1.0193x over previous
//
#include <hip/hip_runtime.h>
#include <hip/hip_bf16.h>

#define B_SZ 2
#define SEQ 4096
#define DMODEL 1024
#define INTER 2048
#define NHEADS 32
#define HDIM 64
#define DSTATE 128
#define DCONV 4
#define CONVDIM 2304
#define PROJDIM 4384
#define CHUNK 256
#define NCHUNK 16
#define ROWS (B_SZ*SEQ)   // 8192
#define NGEMM 4352
#define NMAIN 4096        // main 8-phase cols (16 tiles; grid 512 = 2 clean rounds)

typedef __hip_bfloat16 bf16;
typedef short bfx8 __attribute__((ext_vector_type(8)));
typedef float f32x4 __attribute__((ext_vector_type(4)));

__device__ __forceinline__ float sigmoidf_(float x){ return 1.f/(1.f+expf(-x)); }
__device__ __forceinline__ float b2f(bf16 v){ return __bfloat162float(v); }
__device__ __forceinline__ bf16 f2b(float v){ return __float2bfloat16(v); }
__device__ __forceinline__ float bits2f(unsigned short u){ return __uint_as_float(((unsigned)u) << 16); }
__device__ __forceinline__ unsigned short f2bits(float v){ bf16 t = __float2bfloat16(v); return *(unsigned short*)&t; }

#define MFMA16(a,b,c) __builtin_amdgcn_mfma_f32_16x16x32_bf16(a,b,c,0,0,0)

// ---------------- fallback: zero d_out ----------------
__global__ void zero_out_kernel(float* o, int n){
  int i = blockIdx.x*256 + threadIdx.x;
  if (i < n) o[i] = 0.f;
}

// ---------------- merged cast+transpose for BOTH weights ----------------
__global__ __launch_bounds__(256) void transcast2_kernel(const float* __restrict__ w_in,
    bf16* __restrict__ w_inT, const float* __restrict__ w_out, bf16* __restrict__ w_outT){
  __shared__ float t[64][65];
  int blk = blockIdx.x, tid = threadIdx.x;
  const float* in; bf16* outT; int R, ld, c0, r0;
  if (blk < 1088){
    in = w_in;  outT = w_inT;  R = DMODEL; ld = PROJDIM;
    c0 = (blk % 68)*64; r0 = (blk / 68)*64;
  } else {
    int i = blk - 1088;
    in = w_out; outT = w_outT; R = INTER;  ld = DMODEL;
    c0 = (i & 15)*64;   r0 = (i >> 4)*64;
  }
  #pragma unroll
  for (int i = 0; i < 16; i++){
    int idx = tid + i*256;
    int r = idx >> 6, c = idx & 63;
    t[r][c] = in[(size_t)(r0+r)*ld + c0 + c];
  }
  __syncthreads();
  #pragma unroll
  for (int i = 0; i < 16; i++){
    int idx = tid + i*256;
    int c = idx >> 6, r = idx & 63;
    outT[(size_t)(c0+c)*R + r0 + r] = f2b(t[r][c]);
  }
}

// ================= 8-phase 256x256 MFMA GEMM (m201 template, T2+T3+T4+T5) =================
__device__ __forceinline__ void stage8(const bf16* __restrict__ g, int Kdim,
    int tile0, int k0, char* region, int h, int tid){
  #pragma unroll
  for (int l = 0; l < 2; l++){
    int o  = h*16384 + (l*512 + tid)*16;
    int os = o ^ (((o >> 7) & 7) << 4);
    const bf16* src = g + (size_t)(tile0 + (os >> 7))*Kdim + k0 + ((os & 127) >> 1);
    __builtin_amdgcn_global_load_lds(
      (const __attribute__((address_space(1))) void*)src,
      (__attribute__((address_space(3))) void*)(region + h*16384 + (l*512 + (tid >> 6)*64)*16),
      16, 0, 0);
  }
}
__device__ __forceinline__ bfx8 fr8(const char* region, int row, int colbyte){
  int o = row*128 + colbyte;
  o ^= ((row & 7) << 4);
  return *(const bfx8*)(region + o);
}

#define LGKM0  asm volatile("s_waitcnt lgkmcnt(0)" ::: "memory"); __builtin_amdgcn_sched_barrier(0)
#define VM4    asm volatile("s_waitcnt vmcnt(4)" ::: "memory")
#define VM0    asm volatile("s_waitcnt vmcnt(0)" ::: "memory")
#define BAR    __builtin_amdgcn_s_barrier()
#define PRIO1  __builtin_amdgcn_s_setprio(1)
#define PRIO0  __builtin_amdgcn_s_setprio(0)

#define MFMA_QUAD(MH, NH, BARR)                                                \
  PRIO1;                                                                       \
  _Pragma("unroll") for (int m = 0; m < 4; m++)                                \
    _Pragma("unroll") for (int n = 0; n < 2; n++)                              \
      _Pragma("unroll") for (int kk = 0; kk < 2; kk++)                         \
        acc[(MH)+m][(NH)+n] = MFMA16(aF[m][kk], BARR[n][kk], acc[(MH)+m][(NH)+n]); \
  PRIO0

#define GEMM8_BODY(K_, NBX_)                                                   \
  extern __shared__ char lds[];                                                \
  char* A0 = lds;          char* B0 = lds + 32768;                             \
  char* A1 = lds + 65536;  char* B1 = lds + 98304;                             \
  const int tid = threadIdx.x, lane = tid & 63, wid = tid >> 6;                \
  const int wm = wid >> 2, wn = wid & 3;                                       \
  int nb = (blockIdx.x & 7)*((int)gridDim.x >> 3) + (blockIdx.x >> 3);         \
  const int bx = nb % (NBX_), by = nb / (NBX_);                                \
  const int row0 = by*256, col0 = bx*256;                                      \
  f32x4 acc[8][4] = {};                                                        \
  bfx8 aF[4][2], b01[2][2], b23[2][2];                                         \
  const int frow = lane & 15;                                                  \
  const int fcb0 = (lane >> 4)*16;                                             \
  const int JLAST = (K_)/128 - 1;                                              \
  stage8(Bt, K_, col0, 0,  B0, 0, tid);                                        \
  stage8(Bt, K_, col0, 0,  B0, 1, tid);                                        \
  stage8(A,  K_, row0, 0,  A0, 0, tid);                                        \
  stage8(A,  K_, row0, 0,  A0, 1, tid);                                        \
  stage8(Bt, K_, col0, 64, B1, 0, tid);                                        \
  stage8(Bt, K_, col0, 64, B1, 1, tid);                                        \
  VM4;                                                                         \
  BAR;                                                                         \
  _Pragma("unroll 1")                                                          \
  for (int j = 0; j <= JLAST; j++){                                            \
    const int kO  = j*128 + 64;                                                \
    const int kS1 = (j*128 + 128) & ((K_) - 1);                                \
    const int kS2 = (j*128 + 192) & ((K_) - 1);                                \
    stage8(A, K_, row0, kO, A1, 0, tid);                                       \
    _Pragma("unroll") for (int m = 0; m < 4; m++)                              \
      _Pragma("unroll") for (int kk = 0; kk < 2; kk++)                         \
        aF[m][kk] = fr8(A0, wm*128 + m*16 + frow, kk*64 + fcb0);               \
    _Pragma("unroll") for (int n = 0; n < 2; n++)                              \
      _Pragma("unroll") for (int kk = 0; kk < 2; kk++)                         \
        b01[n][kk] = fr8(B0, wn*64 + n*16 + frow, kk*64 + fcb0);               \
    LGKM0;                                                                     \
    MFMA_QUAD(0, 0, b01);                                                      \
    BAR;                                                                       \
    stage8(A, K_, row0, kO, A1, 1, tid);                                       \
    _Pragma("unroll") for (int n = 0; n < 2; n++)                              \
      _Pragma("unroll") for (int kk = 0; kk < 2; kk++)                         \
        b23[n][kk] = fr8(B0, wn*64 + (n+2)*16 + frow, kk*64 + fcb0);           \
    LGKM0;                                                                     \
    MFMA_QUAD(0, 2, b23);                                                      \
    BAR;                                                                       \
    if (j < JLAST) stage8(Bt, K_, col0, kS1, B0, 0, tid);                      \
    _Pragma("unroll") for (int m = 0; m < 4; m++)                              \
      _Pragma("unroll") for (int kk = 0; kk < 2; kk++)                         \
        aF[m][kk] = fr8(A0, wm*128 + (m+4)*16 + frow, kk*64 + fcb0);           \
    LGKM0;                                                                     \
    MFMA_QUAD(4, 0, b01);                                                      \
    BAR;                                                                       \
    if (j < JLAST){ stage8(Bt, K_, col0, kS1, B0, 1, tid); VM4; }              \
    else { VM0; }                                                              \
    MFMA_QUAD(4, 2, b23);                                                      \
    BAR;                                                                       \
    if (j < JLAST) stage8(A, K_, row0, kS1, A0, 0, tid);                       \
    _Pragma("unroll") for (int m = 0; m < 4; m++)                              \
      _Pragma("unroll") for (int kk = 0; kk < 2; kk++)                         \
        aF[m][kk] = fr8(A1, wm*128 + m*16 + frow, kk*64 + fcb0);               \
    _Pragma("unroll") for (int n = 0; n < 2; n++)                              \
      _Pragma("unroll") for (int kk = 0; kk < 2; kk++)                         \
        b01[n][kk] = fr8(B1, wn*64 + n*16 + frow, kk*64 + fcb0);               \
    LGKM0;                                                                     \
    MFMA_QUAD(0, 0, b01);                                                      \
    BAR;                                                                       \
    if (j < JLAST) stage8(A, K_, row0, kS1, A0, 1, tid);                       \
    _Pragma("unroll") for (int n = 0; n < 2; n++)                              \
      _Pragma("unroll") for (int kk = 0; kk < 2; kk++)                         \
        b23[n][kk] = fr8(B1, wn*64 + (n+2)*16 + frow, kk*64 + fcb0);           \
    LGKM0;                                                                     \
    MFMA_QUAD(0, 2, b23);                                                      \
    BAR;                                                                       \
    if (j < JLAST) stage8(Bt, K_, col0, kS2, B1, 0, tid);                      \
    _Pragma("unroll") for (int m = 0; m < 4; m++)                              \
      _Pragma("unroll") for (int kk = 0; kk < 2; kk++)                         \
        aF[m][kk] = fr8(A1, wm*128 + (m+4)*16 + frow, kk*64 + fcb0);           \
    LGKM0;                                                                     \
    MFMA_QUAD(4, 0, b01);                                                      \
    BAR;                                                                       \
    if (j < JLAST) stage8(Bt, K_, col0, kS2, B1, 1, tid);                      \
    VM4;                                                                       \
    MFMA_QUAD(4, 2, b23);                                                      \
    BAR;                                                                       \
  }

#define SST_STRIDE 280

// main inproj: cols 0..4095 (grid 512 = 2 exact occupancy rounds)
__global__ __launch_bounds__(512, 2) void gemm8_inproj(const bf16* __restrict__ A,
    const bf16* __restrict__ Bt, bf16* __restrict__ z, bf16* __restrict__ xbc){
  GEMM8_BODY(DMODEL, 16)
  unsigned short* sst = (unsigned short*)lds;
  #pragma unroll 1
  for (int half = 0; half < 2; half++){
    if (wm == half){
      #pragma unroll
      for (int m = 0; m < 8; m++)
        #pragma unroll
        for (int n = 0; n < 4; n++)
          #pragma unroll
          for (int r = 0; r < 4; r++){
            int rl = m*16 + (lane>>4)*4 + r;
            sst[rl*SST_STRIDE + wn*64 + n*16 + (lane&15)] = f2bits(acc[m][n][r]);
          }
    }
    BAR;
    #pragma unroll
    for (int i = 0; i < 8; i++){
      int q = tid + i*512;
      int rl = q >> 5, c8 = (q & 31)*8;
      bfx8 v = *(const bfx8*)(sst + rl*SST_STRIDE + c8);
      int gr = row0 + half*128 + rl, gc = col0 + c8;
      if (gc < INTER) *(bfx8*)(z + (size_t)gr*INTER + gc) = v;
      else            *(bfx8*)(xbc + (size_t)gr*CONVDIM + (gc - INTER)) = v;
    }
    BAR;
  }
}

// ================= m97-structure GEMMs (128^2 tile) =================
#define MFMA_GEMM_BODY(K_, ROW0_, COL0_, EPILOGUE)                             \
  __shared__ unsigned short As[128*64];                                        \
  __shared__ unsigned short Bs[128*64];                                        \
  const int tid = threadIdx.x;                                                 \
  const int lane = tid & 63, wid = tid >> 6;                                   \
  const int wm = wid >> 1, wn = wid & 1;                                       \
  const int row0 = (ROW0_), col0 = (COL0_);                                    \
  f32x4 acc[4][4] = {};                                                        \
  const int rstg = wid*32 + ((lane>>3)&7);                                     \
  const int kstg = (lane&7)*8;                                                 \
  for (int k0 = 0; k0 < (K_); k0 += 64){                                       \
    _Pragma("unroll")                                                          \
    for (int j = 0; j < 4; j++){                                               \
      const bf16* gA = A + (size_t)(row0 + rstg + j*8)*(K_) + k0 + kstg;       \
      __builtin_amdgcn_global_load_lds(                                        \
        (const __attribute__((address_space(1))) void*)gA,                     \
        (__attribute__((address_space(3))) void*)(As + (wid*32 + j*8)*64),     \
        16, 0, 0);                                                             \
      const bf16* gB = Bt + (size_t)(col0 + rstg + j*8)*(K_) + k0 + kstg;      \
      __builtin_amdgcn_global_load_lds(                                        \
        (const __attribute__((address_space(1))) void*)gB,                     \
        (__attribute__((address_space(3))) void*)(Bs + (wid*32 + j*8)*64),     \
        16, 0, 0);                                                             \
    }                                                                          \
    __syncthreads();                                                           \
    _Pragma("unroll")                                                          \
    for (int kk = 0; kk < 2; kk++){                                            \
      bfx8 af[4], bfr[4];                                                      \
      _Pragma("unroll")                                                        \
      for (int m = 0; m < 4; m++)                                              \
        af[m] = *(const bfx8*)(As + (wm*64 + m*16 + (lane&15))*64              \
                               + kk*32 + (lane>>4)*8);                         \
      _Pragma("unroll")                                                        \
      for (int n = 0; n < 4; n++)                                              \
        bfr[n] = *(const bfx8*)(Bs + (wn*64 + n*16 + (lane&15))*64             \
                                + kk*32 + (lane>>4)*8);                        \
      _Pragma("unroll")                                                        \
      for (int m = 0; m < 4; m++)                                              \
        _Pragma("unroll")                                                      \
        for (int n = 0; n < 4; n++)                                            \
          acc[m][n] = MFMA16(af[m], bfr[n], acc[m][n]);                        \
    }                                                                          \
    __syncthreads();                                                           \
  }                                                                            \
  _Pragma("unroll")                                                            \
  for (int m = 0; m < 4; m++){                                                 \
    int row = row0 + wm*64 + m*16 + (lane>>4)*4;                               \
    _Pragma("unroll")                                                          \
    for (int n = 0; n < 4; n++){                                               \
      int col = col0 + wn*64 + n*16 + (lane&15);                               \
      _Pragma("unroll")                                                        \
      for (int r = 0; r < 4; r++){                                             \
        float v = acc[m][n][r];                                                \
        int rr = row + r;                                                      \
        EPILOGUE                                                               \
      }                                                                        \
    }                                                                          \
  }

__global__ __launch_bounds__(256) void gemm_mfma_inproj(const bf16* __restrict__ A,
    const bf16* __restrict__ Bt, bf16* __restrict__ z, bf16* __restrict__ xbc){
  MFMA_GEMM_BODY(DMODEL, blockIdx.y*128, blockIdx.x*128,
    if (col < INTER) z[(size_t)rr*INTER + col] = f2b(v);
    else             xbc[(size_t)rr*CONVDIM + (col - INTER)] = f2b(v);
  )
}
// strip: inproj cols 4096..4351 (xbc cols 2048..2303); Bt pre-offset
__global__ __launch_bounds__(256) void gemm_mfma_strip(const bf16* __restrict__ A,
    const bf16* __restrict__ Bt, bf16* __restrict__ xbc){
  MFMA_GEMM_BODY(DMODEL, blockIdx.y*128, blockIdx.x*128,
    xbc[(size_t)rr*CONVDIM + 2048 + col] = f2b(v);
  )
}
// outproj: 1D grid 512, per-XCD row-chunk swizzle
__global__ __launch_bounds__(256) void gemm_mfma_outproj(const bf16* __restrict__ A,
    const bf16* __restrict__ Bt, float* __restrict__ C){
  int nbo = (blockIdx.x & 7)*64 + (blockIdx.x >> 3);
  MFMA_GEMM_BODY(INTER, (nbo >> 3)*128, (nbo & 7)*128,
    C[(size_t)rr*DMODEL + col] = v;
  )
}

// ---------------- split-K fp32 dt GEMM + fused u->bf16 cast ----------------
__global__ __launch_bounds__(256) void dt_partial(const float* __restrict__ u,
    const float* __restrict__ w_in, float* __restrict__ partial,
    unsigned short* __restrict__ u_bf){
  __shared__ float wsm[128][33];
  __shared__ float us[32][133];
  int ks = blockIdx.x, row0 = blockIdx.y*32;
  int k0 = ks*128;
  int tid = threadIdx.x;
  #pragma unroll
  for (int i = 0; i < 16; i++){
    int idx = tid + i*256;
    wsm[idx >> 5][idx & 31] = w_in[(size_t)(k0 + (idx >> 5))*PROJDIM + NGEMM + (idx & 31)];
  }
  #pragma unroll
  for (int i = 0; i < 4; i++){
    int idx = tid + i*256;
    int r = idx >> 5, c4 = idx & 31;
    float4 v = *(const float4*)(u + (size_t)(row0 + r)*DMODEL + k0 + c4*4);
    us[r][c4*4+0] = v.x; us[r][c4*4+1] = v.y; us[r][c4*4+2] = v.z; us[r][c4*4+3] = v.w;
    ushort4 w;
    w.x = f2bits(v.x); w.y = f2bits(v.y); w.z = f2bits(v.z); w.w = f2bits(v.w);
    *(ushort4*)(u_bf + (size_t)(row0 + r)*DMODEL + k0 + c4*4) = w;
  }
  __syncthreads();
  int col = tid & 31, r0 = tid >> 5;
  float acc[4] = {};
  #pragma unroll 4
  for (int kk4 = 0; kk4 < 32; kk4++){
    float4 uv[4];
    #pragma unroll
    for (int i = 0; i < 4; i++)
      uv[i] = *(const float4*)&us[r0 + i*8][kk4*4];
    #pragma unroll
    for (int j = 0; j < 4; j++){
      float wv = wsm[kk4*4 + j][col];
      #pragma unroll
      for (int i = 0; i < 4; i++){
        float uvj = (j == 0) ? uv[i].x : (j == 1) ? uv[i].y : (j == 2) ? uv[i].z : uv[i].w;
        acc[i] = fmaf(uvj, wv, acc[i]);
      }
    }
  }
  #pragma unroll
  for (int i = 0; i < 4; i++)
    partial[((size_t)ks*ROWS + row0 + r0 + i*8)*NHEADS + col] = acc[i];
}

// ---------------- conv1d + silu + split (sliding-window) ----------------
__global__ __launch_bounds__(256) void conv_kernel(const bf16* __restrict__ xbc,
    const float* __restrict__ cw, const float* __restrict__ cb,
    bf16* __restrict__ x, bf16* __restrict__ Bm, bf16* __restrict__ Cm){
  int ch = blockIdx.x*256 + threadIdx.x;
  int t0 = blockIdx.y*64;
  int b  = blockIdx.z;
  float w0 = cw[ch*4+0], w1 = cw[ch*4+1], w2 = cw[ch*4+2], w3 = cw[ch*4+3];
  float bia = cb[ch];
  const bf16* src = xbc + (size_t)(b*SEQ)*CONVDIM + ch;
  float xm3 = 0.f, xm2 = 0.f, xm1 = 0.f;
  if (t0 > 0){
    xm3 = b2f(src[(size_t)(t0-3)*CONVDIM]);
    xm2 = b2f(src[(size_t)(t0-2)*CONVDIM]);
    xm1 = b2f(src[(size_t)(t0-1)*CONVDIM]);
  }
  bf16* dst; size_t dstride;
  if (ch < INTER)             { dst = x  + (size_t)(b*SEQ + t0)*INTER  + ch;                 dstride = INTER; }
  else if (ch < INTER+DSTATE) { dst = Bm + (size_t)(b*SEQ + t0)*DSTATE + (ch-INTER);         dstride = DSTATE; }
  else                        { dst = Cm + (size_t)(b*SEQ + t0)*DSTATE + (ch-INTER-DSTATE);  dstride = DSTATE; }
  #pragma unroll 4
  for (int i = 0; i < 64; i++){
    float xc = b2f(src[(size_t)(t0+i)*CONVDIM]);
    float acc = bia;
    acc = fmaf(xm3, w0, acc);
    acc = fmaf(xm2, w1, acc);
    acc = fmaf(xm1, w2, acc);
    acc = fmaf(xc,  w3, acc);
    float v = acc * sigmoidf_(acc);
    dst[(size_t)i*dstride] = f2b(v);
    xm3 = xm2; xm2 = xm1; xm1 = xc;
  }
}

// ---------------- fused: 8-way reduce + bias + softplus -> dt; cumsum(dt*A) -> Acum ----------------
// NOTE: dt/Acum alias the xbc TAIL — must launch after conv.
__global__ __launch_bounds__(256) void acum_fused(const float* __restrict__ partial,
    const float* __restrict__ dt_bias, const float* __restrict__ A_log,
    float* __restrict__ dt, float* __restrict__ Acum){
  int bi = blockIdx.x;
  int c = bi & 15; int h = (bi >> 4) & 31; int b = bi >> 9;
  int l = threadIdx.x;
  __shared__ float sbuf[CHUNK];
  int t = c*CHUNK + l;
  size_t idx = (size_t)(b*SEQ + t)*NHEADS + h;
  float s = dt_bias[h];
  #pragma unroll
  for (int ks = 0; ks < 8; ks++)
    s += partial[(size_t)ks*ROWS*NHEADS + idx];
  float v = (s > 20.f) ? s : log1pf(expf(s));
  dt[idx] = v;
  float A = -expf(A_log[h]);
  sbuf[l] = v * A;
  __syncthreads();
  for (int off = 1; off < CHUNK; off <<= 1){
    float add = (l >= off) ? sbuf[l-off] : 0.f;
    __syncthreads();
    sbuf[l] += add;
    __syncthreads();
  }
  Acum[(size_t)bi*CHUNK + l] = sbuf[l];
}

// ---------------- head-shared scores (dense task list): S[bc][l][s] = C·B^T ----------------
__global__ __launch_bounds__(256) void scores_mfma(const bf16* __restrict__ Bm,
    const bf16* __restrict__ Cm, bf16* __restrict__ S){
  int bc = blockIdx.x;
  int b = bc >> 4, c = bc & 15;
  int tid = threadIdx.x, lane = tid & 63;
  int task = blockIdx.y*4 + (tid >> 6);
  if (task >= 10) return;
  int rb = (task >= 6) ? 3 : (task >= 3) ? 2 : (task >= 1) ? 1 : 0;
  int j = task - rb*(rb+1)/2;
  const bf16* Crow = Cm + (size_t)(b*SEQ + c*CHUNK)*DSTATE;
  const bf16* Brow = Bm + (size_t)(b*SEQ + c*CHUNK)*DSTATE;
  f32x4 acc[4][4] = {};
  #pragma unroll
  for (int kk = 0; kk < 4; kk++){
    bfx8 af[4], bfr[4];
    #pragma unroll
    for (int m = 0; m < 4; m++)
      af[m] = *(const bfx8*)(Crow + (size_t)(rb*64 + m*16 + (lane&15))*DSTATE + kk*32 + (lane>>4)*8);
    #pragma unroll
    for (int n = 0; n < 4; n++)
      bfr[n] = *(const bfx8*)(Brow + (size_t)(j*64 + n*16 + (lane&15))*DSTATE + kk*32 + (lane>>4)*8);
    #pragma unroll
    for (int m = 0; m < 4; m++)
      #pragma unroll
      for (int n = 0; n < 4; n++)
        acc[m][n] = MFMA16(af[m], bfr[n], acc[m][n]);
  }
  bf16* dst = S + (size_t)bc*CHUNK*CHUNK;
  #pragma unroll
  for (int m = 0; m < 4; m++)
    #pragma unroll
    for (int n = 0; n < 4; n++)
      #pragma unroll
      for (int r = 0; r < 4; r++)
        dst[(size_t)(rb*64 + m*16 + (lane>>4)*4 + r)*CHUNK + j*64 + n*16 + (lane&15)]
          = f2b(acc[m][n][r]);
}

// ---------------- build XW_T + BT ----------------
__global__ __launch_bounds__(256) void xwt_kernel(const bf16* __restrict__ x,
    const bf16* __restrict__ Bm, const float* __restrict__ dt,
    const float* __restrict__ Acum, bf16* __restrict__ xwt, bf16* __restrict__ bt){
  int pt = blockIdx.x, tt = blockIdx.y, b = blockIdx.z;
  int tid = threadIdx.x;
  __shared__ unsigned short tile[64][72];
  __shared__ float wf[64];
  int t0 = tt*64;
  if (pt < 32){
    int h = pt, c = t0 >> 8;
    if (tid < 64){
      const float* AcB = Acum + ((size_t)(b*NHEADS + h)*NCHUNK + c)*CHUNK;
      int t = t0 + tid;
      wf[tid] = dt[(size_t)(b*SEQ + t)*NHEADS + h] * expf(AcB[255] - AcB[t & 255]);
    }
    __syncthreads();
    const bf16* src = x + (size_t)(b*SEQ + t0)*INTER + pt*64;
    #pragma unroll
    for (int i = 0; i < 2; i++){
      int u = tid + i*256;
      int r = u >> 3, po = (u & 7)*8;
      bfx8 v = *(const bfx8*)(src + (size_t)r*INTER + po);
      float d = wf[r];
      #pragma unroll
      for (int j = 0; j < 8; j++)
        tile[r][po + j] = f2bits(bits2f((unsigned short)v[j]) * d);
    }
    __syncthreads();
    bf16* dst = xwt + ((size_t)(b*INTER) + pt*64)*SEQ + t0;
    #pragma unroll
    for (int i = 0; i < 2; i++){
      int u = tid + i*256;
      int p = u >> 3, tc = (u & 7)*8;
      bfx8 v;
      #pragma unroll
      for (int j = 0; j < 8; j++) v[j] = (short)tile[tc + j][p];
      *(bfx8*)(dst + (size_t)p*SEQ + tc) = v;
    }
  } else {
    int n0 = (pt - 32)*64;
    const bf16* src = Bm + (size_t)(b*SEQ + t0)*DSTATE + n0;
    #pragma unroll
    for (int i = 0; i < 2; i++){
      int u = tid + i*256;
      int r = u >> 3, po = (u & 7)*8;
      bfx8 v = *(const bfx8*)(src + (size_t)r*DSTATE + po);
      *(bfx8*)&tile[r][po] = v;
    }
    __syncthreads();
    bf16* dst = bt + ((size_t)(b*DSTATE) + n0)*SEQ + t0;
    #pragma unroll
    for (int i = 0; i < 2; i++){
      int u = tid + i*256;
      int p = u >> 3, tc = (u & 7)*8;
      bfx8 v;
      #pragma unroll
      for (int j = 0; j < 8; j++) v[j] = (short)tile[tc + j][p];
      *(bfx8*)(dst + (size_t)p*SEQ + tc) = v;
    }
  }
}

// ---------------- MFMA chunk-states ----------------
__global__ __launch_bounds__(256) void chunk_states_mfma(const bf16* __restrict__ xwt,
    const bf16* __restrict__ bt, float* __restrict__ states){
  int bi = blockIdx.x;
  int h = bi & 31; int c = (bi >> 5) & 15; int b = bi >> 9;
  int tid = threadIdx.x, lane = tid & 63, w = tid >> 6;
  int wm = w >> 1, wn = w & 1;
  const bf16* Arow = xwt + ((size_t)(b*INTER) + h*64)*SEQ + c*CHUNK;
  const bf16* Brow = bt + (size_t)(b*DSTATE)*SEQ + c*CHUNK;
  f32x4 acc[2][4] = {};
  #pragma unroll
  for (int kk = 0; kk < 8; kk++){
    bfx8 af[2], bfr[4];
    #pragma unroll
    for (int m = 0; m < 2; m++)
      af[m] = *(const bfx8*)(Arow + (size_t)(wm*32 + m*16 + (lane&15))*SEQ + kk*32 + (lane>>4)*8);
    #pragma unroll
    for (int n = 0; n < 4; n++)
      bfr[n] = *(const bfx8*)(Brow + (size_t)(wn*64 + n*16 + (lane&15))*SEQ + kk*32 + (lane>>4)*8);
    #pragma unroll
    for (int m = 0; m < 2; m++)
      #pragma unroll
      for (int n = 0; n < 4; n++)
        acc[m][n] = MFMA16(af[m], bfr[n], acc[m][n]);
  }
  float* dst = states + (size_t)bi*HDIM*DSTATE;
  #pragma unroll
  for (int m = 0; m < 2; m++)
    #pragma unroll
    for (int n = 0; n < 4; n++)
      #pragma unroll
      for (int r = 0; r < 4; r++){
        int p = wm*32 + m*16 + (lane>>4)*4 + r;
        int nn = wn*64 + n*16 + (lane&15);
        dst[(size_t)p*DSTATE + nn] = acc[m][n][r];
      }
}

// ---------------- inter-chunk scan ----------------
__global__ __launch_bounds__(256) void scan_kernel(float* __restrict__ states,
    const float* __restrict__ Acum){
  int idx = blockIdx.x*256 + threadIdx.x;
  int n = idx & 127; int p = (idx >> 7) & 63; int h = (idx >> 13) & 31; int b = idx >> 18;
  float R = 0.f;
  for (int c = 0; c < NCHUNK; c++){
    size_t o = (((size_t)((b*NCHUNK + c)*NHEADS + h))*HDIM + p)*DSTATE + n;
    float s = states[o];
    states[o] = R;
    float dA = expf(Acum[((size_t)(b*NHEADS + h)*NCHUNK + c)*CHUNK + CHUNK-1]);
    R = R*dA + s;
  }
}

// ================= fused MFMA Y kernel (R18-verified: wave w owns rows w*64..w*64+63) =================
__global__ __launch_bounds__(256, 3) void ydiag_mfma(
    const bf16* x, const float* __restrict__ dt,
    const float* __restrict__ Acum, const bf16* __restrict__ Sg,
    const bf16* __restrict__ Cm, const float* __restrict__ states,
    const float* __restrict__ Dp, bf16* y){
  int bi = blockIdx.x;
  int h = bi & 31; int c = (bi >> 5) & 15; int b = bi >> 9;
  int bc = b*NCHUNK + c;
  int tid = threadIdx.x, lane = tid & 63, w = tid >> 6;

  __shared__ unsigned short XdtT[64*264];
  __shared__ unsigned short pool[128*72];
  __shared__ float Acs[CHUNK];
  __shared__ float dts[CHUNK];

  const float* AcBase = Acum + ((size_t)(b*NHEADS + h)*NCHUNK + c)*CHUNK;
  Acs[tid] = AcBase[tid];
  dts[tid] = dt[(size_t)(b*SEQ + c*CHUNK + tid)*NHEADS + h];
  {
    const float* src = states + (size_t)bi*HDIM*DSTATE;
    #pragma unroll
    for (int i = 0; i < 8; i++){
      int q = tid + i*256;
      float4 v = ((const float4*)src)[q];
      int p = q >> 5, n = (q & 31)*4;
      ushort4 o;
      o.x = f2bits(v.x); o.y = f2bits(v.y); o.z = f2bits(v.z); o.w = f2bits(v.w);
      *(ushort4*)(pool + p*136 + n) = o;
    }
  }
  __syncthreads();

  const bf16* Crow = Cm + (size_t)(b*SEQ + c*CHUNK)*DSTATE;

  f32x4 accY[4][4] = {};
  #pragma unroll
  for (int kk = 0; kk < 4; kk++){
    bfx8 af[4], bfr[4];
    #pragma unroll
    for (int m = 0; m < 4; m++)
      af[m] = *(const bfx8*)(Crow + (size_t)(w*64 + m*16 + (lane&15))*DSTATE + kk*32 + (lane>>4)*8);
    #pragma unroll
    for (int n = 0; n < 4; n++)
      bfr[n] = *(const bfx8*)(pool + (n*16 + (lane&15))*136 + kk*32 + (lane>>4)*8);
    #pragma unroll
    for (int m = 0; m < 4; m++)
      #pragma unroll
      for (int n = 0; n < 4; n++)
        accY[m][n] = MFMA16(af[m], bfr[n], accY[m][n]);
  }
  {
    float eAl[4][4];
    #pragma unroll
    for (int m = 0; m < 4; m++)
      #pragma unroll
      for (int r = 0; r < 4; r++)
        eAl[m][r] = expf(Acs[w*64 + m*16 + (lane>>4)*4 + r]);
    #pragma unroll
    for (int m = 0; m < 4; m++)
      #pragma unroll
      for (int n = 0; n < 4; n++)
        #pragma unroll
        for (int r = 0; r < 4; r++)
          accY[m][n][r] *= eAl[m][r];
  }
  __syncthreads();

  #pragma unroll 1
  for (int q = 0; q < 2; q++){
    const bf16* xg = x + (size_t)(b*SEQ + c*CHUNK + q*128)*INTER + h*HDIM;
    #pragma unroll
    for (int i = 0; i < 4; i++){
      int u = tid + i*256;
      int s = u >> 3, p0 = (u & 7)*8;
      bfx8 v = *(const bfx8*)(xg + (size_t)s*INTER + p0);
      float d = dts[q*128 + s];
      bfx8 o;
      #pragma unroll
      for (int j = 0; j < 8; j++)
        o[j] = (short)f2bits(bits2f((unsigned short)v[j]) * d);
      *(bfx8*)(pool + s*72 + p0) = o;
    }
    __syncthreads();
    {
      int p = tid & 63, sb = tid >> 6;
      #pragma unroll
      for (int i = 0; i < 4; i++){
        int s0 = (sb + i*4)*8;
        bfx8 v;
        #pragma unroll
        for (int j = 0; j < 8; j++)
          v[j] = (short)pool[(s0 + j)*72 + p];
        *(bfx8*)(XdtT + p*264 + q*128 + s0) = v;
      }
    }
    __syncthreads();
  }

  const bf16* Srow = Sg + (size_t)bc*CHUNK*CHUNK + (size_t)(w*64)*CHUNK;
  float Dh = Dp[h];
  for (int j = 0; j <= w; j++){
    int s0 = j*64;
    bfx8 wfr[4][2];
    if (j < w){
      float m_ = Acs[s0 + 63];
      float rowf[4];
      #pragma unroll
      for (int m = 0; m < 4; m++)
        rowf[m] = expf(Acs[w*64 + m*16 + (lane&15)] - m_);
      #pragma unroll
      for (int kk = 0; kk < 2; kk++){
        float colf[8];
        #pragma unroll
        for (int t = 0; t < 8; t++)
          colf[t] = expf(m_ - Acs[s0 + kk*32 + (lane>>4)*8 + t]);
        #pragma unroll
        for (int m = 0; m < 4; m++){
          bfx8 raw = *(const bfx8*)(Srow + (size_t)(m*16 + (lane&15))*CHUNK + s0 + kk*32 + (lane>>4)*8);
          bfx8 o;
          #pragma unroll
          for (int t = 0; t < 8; t++)
            o[t] = (short)f2bits(bits2f((unsigned short)raw[t]) * rowf[m] * colf[t]);
          wfr[m][kk] = o;
        }
      }
    } else {
      #pragma unroll
      for (int kk = 0; kk < 2; kk++)
        #pragma unroll
        for (int m = 0; m < 4; m++){
          int lg = w*64 + m*16 + (lane&15);
          float Al = Acs[lg];
          bfx8 raw = *(const bfx8*)(Srow + (size_t)(m*16 + (lane&15))*CHUNK + s0 + kk*32 + (lane>>4)*8);
          bfx8 o;
          #pragma unroll
          for (int t = 0; t < 8; t++){
            int sg = s0 + kk*32 + (lane>>4)*8 + t;
            float v;
            if (sg > lg)       v = 0.f;
            else if (sg == lg) v = bits2f((unsigned short)raw[t]) + Dh/dts[lg];
            else               v = bits2f((unsigned short)raw[t]) * expf(Al - Acs[sg]);
            o[t] = (short)f2bits(v);
          }
          wfr[m][kk] = o;
        }
    }
    #pragma unroll
    for (int kk = 0; kk < 2; kk++){
      bfx8 bfr[4];
      #pragma unroll
      for (int n = 0; n < 4; n++)
        bfr[n] = *(const bfx8*)(XdtT + (n*16 + (lane&15))*264 + s0 + kk*32 + (lane>>4)*8);
      #pragma unroll
      for (int m = 0; m < 4; m++)
        #pragma unroll
        for (int n = 0; n < 4; n++)
          accY[m][n] = MFMA16(wfr[m][kk], bfr[n], accY[m][n]);
    }
  }
  bf16* yg = y + (size_t)(b*SEQ + c*CHUNK)*INTER + h*HDIM;
  #pragma unroll
  for (int m = 0; m < 4; m++)
    #pragma unroll
    for (int n = 0; n < 4; n++)
      #pragma unroll
      for (int r = 0; r < 4; r++)
        yg[(size_t)(w*64 + m*16 + (lane>>4)*4 + r)*INTER + n*16 + (lane&15)]
          = f2b(accY[m][n][r]);
}

// ---------------- gate + RMSNorm (vectorized bfx8 loads/stores) ----------------
__global__ __launch_bounds__(256) void gatenorm_kernel(bf16* __restrict__ y,
    const bf16* __restrict__ z, const float* __restrict__ nw){
  int row = blockIdx.x;
  const bf16* zr = z + (size_t)row*INTER;
  bf16* yr = y + (size_t)row*INTER;
  int tid = threadIdx.x;
  bfx8 zv = *(const bfx8*)(zr + tid*8);
  bfx8 yv = *(const bfx8*)(yr + tid*8);
  float g[8]; float ss = 0.f;
  #pragma unroll
  for (int j = 0; j < 8; j++){
    float zf = bits2f((unsigned short)zv[j]);
    float gv = bits2f((unsigned short)yv[j]) * zf * sigmoidf_(zf);
    g[j] = gv; ss += gv*gv;
  }
  #pragma unroll
  for (int off = 32; off > 0; off >>= 1) ss += __shfl_down(ss, off);
  __shared__ float red[4];
  __shared__ float stot;
  int lane = tid & 63, wid = tid >> 6;
  if (lane == 0) red[wid] = ss;
  __syncthreads();
  if (tid == 0) stot = rsqrtf((red[0]+red[1]+red[2]+red[3]) * (1.f/INTER) + 1e-5f);
  __syncthreads();
  float sc = stot;
  float4 nw0 = *(const float4*)(nw + tid*8);
  float4 nw1 = *(const float4*)(nw + tid*8 + 4);
  bfx8 o;
  o[0] = (short)f2bits(g[0]*sc*nw0.x);
  o[1] = (short)f2bits(g[1]*sc*nw0.y);
  o[2] = (short)f2bits(g[2]*sc*nw0.z);
  o[3] = (short)f2bits(g[3]*sc*nw0.w);
  o[4] = (short)f2bits(g[4]*sc*nw1.x);
  o[5] = (short)f2bits(g[5]*sc*nw1.y);
  o[6] = (short)f2bits(g[6]*sc*nw1.z);
  o[7] = (short)f2bits(g[7]*sc*nw1.w);
  *(bfx8*)(yr + tid*8) = o;
}

extern "C" void kernel_launch(void* const* d_in, const int* in_sizes, int n_in,
                              void* d_out, int out_size, void* d_ws, size_t ws_size,
                              hipStream_t stream){
  const float* u    = (const float*)d_in[0];
  const float* w_in = (const float*)d_in[1];
  const float* cw   = (const float*)d_in[2];
  const float* cb   = (const float*)d_in[3];
  const float* dtb  = (const float*)d_in[4];
  const float* Alog = (const float*)d_in[5];
  const float* Dp   = (const float*)d_in[6];
  const float* nw   = (const float*)d_in[7];
  const float* w_out= (const float*)d_in[8];
  float* out = (float*)d_out;
  char* ws = (char*)d_ws;

  // layout (bytes)
  const size_t OFF_Z     = 0;
  const size_t OFF_XBC   = 33554432;
  const size_t OFF_DT    = 67108864;       // xbc TAIL — write only after conv!
  const size_t OFF_ACUM  = 68157440;       // xbc TAIL — write only after conv!
  const size_t OFF_X     = 71303168;       // y aliases
  const size_t OFF_UBF   = 104857600;      // XW_T aliases after inproj
  const size_t OFF_WINT  = 121634816;
  const size_t OFF_XWT   = 104857600;
  const size_t OFF_BM    = 138412032;
  const size_t OFF_CM    = 140509184;
  const size_t OFF_BT    = 143654912;
  const size_t OFF_WOUTT = 145752064;
  const size_t OFF_PART  = 149946368;      // S aliases after acum_fused
  const size_t NEED      = 158334976;

  if (ws_size < NEED){
    zero_out_kernel<<<(out_size + 255)/256, 256, 0, stream>>>(out, out_size);
    return;
  }

  bf16*  z      = (bf16*)(ws + OFF_Z);
  bf16*  xbc    = (bf16*)(ws + OFF_XBC);
  float* states = (float*)(ws + OFF_XBC);
  float* dt     = (float*)(ws + OFF_DT);
  float* Acum   = (float*)(ws + OFF_ACUM);
  bf16*  x      = (bf16*)(ws + OFF_X);
  bf16*  y      = (bf16*)(ws + OFF_X);
  bf16*  u_bf   = (bf16*)(ws + OFF_UBF);
  bf16*  w_inT  = (bf16*)(ws + OFF_WINT);
  bf16*  xwt    = (bf16*)(ws + OFF_XWT);
  bf16*  Bm     = (bf16*)(ws + OFF_BM);
  bf16*  Cm     = (bf16*)(ws + OFF_CM);
  bf16*  bt     = (bf16*)(ws + OFF_BT);
  bf16*  w_outT = (bf16*)(ws + OFF_WOUTT);
  float* part   = (float*)(ws + OFF_PART);
  bf16*  S      = (bf16*)(ws + OFF_PART);

  bool use8 = true;
  if (hipFuncSetAttribute((const void*)gemm8_inproj,
        hipFuncAttributeMaxDynamicSharedMemorySize, 131072) != hipSuccess) use8 = false;

  // 1) split-K dt partials + fused u->bf16 cast
  dt_partial<<<dim3(8, ROWS/32), 256, 0, stream>>>(u, w_in, part, (unsigned short*)u_bf);
  // 2) merged transcast
  transcast2_kernel<<<1600, 256, 0, stream>>>(w_in, w_inT, w_out, w_outT);
  // 3) inproj GEMM: main + strip
  if (use8){
    gemm8_inproj<<<512, 512, 131072, stream>>>(u_bf, w_inT, z, xbc);
    gemm_mfma_strip<<<dim3(2, ROWS/128), 256, 0, stream>>>(u_bf, w_inT + (size_t)NMAIN*DMODEL, xbc);
  } else {
    gemm_mfma_inproj<<<dim3(NGEMM/128, ROWS/128), 256, 0, stream>>>(u_bf, w_inT, z, xbc);
  }
  // 4) conv (MUST precede acum_fused: dt/Acum alias xbc tail)
  conv_kernel<<<dim3(9, SEQ/64, B_SZ), 256, 0, stream>>>(xbc, cw, cb, x, Bm, Cm);
  // 5) reduce+softplus -> dt, cumsum -> Acum
  acum_fused<<<B_SZ*NHEADS*NCHUNK, 256, 0, stream>>>(part, dtb, Alog, dt, Acum);
  // 6) head-shared scores
  scores_mfma<<<dim3(B_SZ*NCHUNK, 3), 256, 0, stream>>>(Bm, Cm, S);
  // 7) weighted transpose XW_T + BT
  xwt_kernel<<<dim3(34, 64, 2), 256, 0, stream>>>(x, Bm, dt, Acum, xwt, bt);
  // 8) MFMA chunk-states
  chunk_states_mfma<<<B_SZ*NCHUNK*NHEADS, 256, 0, stream>>>(xwt, bt, states);
  // 9) inter-chunk scan
  scan_kernel<<<(B_SZ*NHEADS*HDIM*DSTATE)/256, 256, 0, stream>>>(states, Acum);
  // 10) fused MFMA Y (R18-verified wave layout)
  ydiag_mfma<<<B_SZ*NCHUNK*NHEADS, 256, 0, stream>>>(x, dt, Acum, S, Cm, states, Dp, y);
  // 11) gate + RMSNorm
  gatenorm_kernel<<<ROWS, 256, 0, stream>>>(y, z, nw);
  // 12) out_proj
  gemm_mfma_outproj<<<512, 256, 0, stream>>>(y, w_outT, out);
}